// Round 2
// baseline (1996.903 us; speedup 1.0000x reference)
//
#include <hip/hip_runtime.h>

#define DIM   256
#define KSEQ  2048
#define BATCH 256
#define NROWS (KSEQ * BATCH)        // 524288 flattened (k,b) rows
#define MTILES 4
#define STRIPROWS (MTILES * 16)     // 64 rows per strip
#define NSTRIPS (NROWS / STRIPROWS) // 8192
#define BLOCKS 256
#define WAVES_PER_BLOCK 8           // 512 threads
#define TOTALWAVES (BLOCKS * WAVES_PER_BLOCK)  // 2048 -> 4 strips/wave

typedef __attribute__((ext_vector_type(8))) __bf16 bf16x8;
typedef __attribute__((ext_vector_type(4))) float  floatx4;
typedef __attribute__((ext_vector_type(8))) short  short8;

__device__ __forceinline__ unsigned short f2bf_bits(float f) {
    unsigned u = __builtin_bit_cast(unsigned, f);
    u += 0x7fffu + ((u >> 16) & 1u);          // round-to-nearest-even
    return (unsigned short)(u >> 16);
}

__device__ __forceinline__ __bf16 f2bf(float f) {
    return __builtin_bit_cast(__bf16, f2bf_bits(f));
}

__device__ __forceinline__ float fast_tanh(float x) {
    float e = __expf(2.0f * x);
    return 1.0f - 2.0f * __builtin_amdgcn_rcpf(e + 1.0f);
}

// Kernel 1: qpbT[d,b] = sum_e query[b,e]*Wq[d,e] + bq[d] + bref[d]  (TRANSPOSED)
__global__ void qpb_kernel(const float* __restrict__ query,
                           const float* __restrict__ Wq,
                           const float* __restrict__ bq,
                           const float* __restrict__ bref,
                           float* __restrict__ qpbT) {
    __shared__ float qs[DIM];
    const int b = blockIdx.x;
    const int d = threadIdx.x;
    qs[d] = query[b * DIM + d];
    __syncthreads();
    const float* wrow = Wq + d * DIM;
    float acc = 0.f;
#pragma unroll 8
    for (int e = 0; e < DIM; ++e) acc += qs[e] * wrow[e];
    qpbT[d * BATCH + b] = acc + bq[d] + bref[d];
}

// Kernel 2: fused ref-GEMM + tanh-dot + logit clip.
// 256 blocks x 512 threads (8 waves, 2/SIMD -> 256 VGPR budget, no spills).
__global__ __launch_bounds__(512, 2) void attn_kernel(
        const float* __restrict__ enc,    // (NROWS, DIM) fp32
        const float* __restrict__ qpbT,   // (DIM, BATCH) fp32 = q + bref, transposed
        const float* __restrict__ Wref,   // (DIM, DIM) fp32
        const float* __restrict__ v,      // (DIM,)
        float* __restrict__ out) {        // (BATCH, KSEQ)
    __shared__ short wlds[DIM * DIM];     // 128 KiB bf16 Wref, xor-swizzled 16B chunks

    const int tid = threadIdx.x;

    // ---- Stage Wref -> LDS as bf16. Chunk = 8 bf16 (16B), 32 chunks/row.
    // Chunk c of row d stored at chunk (c ^ (d & 15)).
#pragma unroll
    for (int it = 0; it < 16; ++it) {
        const int flat = it * 512 + tid;      // 8192 chunks
        const int d = flat >> 5;
        const int c = flat & 31;
        const float* src = Wref + d * DIM + c * 8;
        float4 f0 = *(const float4*)(src);
        float4 f1 = *(const float4*)(src + 4);
        short8 sv;
        sv[0] = (short)f2bf_bits(f0.x); sv[1] = (short)f2bf_bits(f0.y);
        sv[2] = (short)f2bf_bits(f0.z); sv[3] = (short)f2bf_bits(f0.w);
        sv[4] = (short)f2bf_bits(f1.x); sv[5] = (short)f2bf_bits(f1.y);
        sv[6] = (short)f2bf_bits(f1.z); sv[7] = (short)f2bf_bits(f1.w);
        *(short8*)&wlds[d * DIM + ((c ^ (d & 15)) << 3)] = sv;
    }
    __syncthreads();

    const int lane = tid & 63;
    const int wave = tid >> 6;
    const int n = lane & 15;     // MFMA A-row residue / B-col / C-col index
    const int g = lane >> 4;     // quad group

    // Preload v: lane needs v[t*16+n] for each of the 16 n-tiles.
    float vreg[16];
#pragma unroll
    for (int t = 0; t < 16; ++t) vreg[t] = v[t * 16 + n];

    // Grid-stride over 64-row strips; stride rows = 2048*64 = 0 mod 256,
    // so each wave's batch window bbase is constant.
    for (int strip = blockIdx.x * WAVES_PER_BLOCK + wave; strip < NSTRIPS;
         strip += TOTALWAVES) {
        const int rowbase = strip * STRIPROWS;
        const int bbase = rowbase & 255;
        const float* qbase = qpbT + bbase + g * 4;   // + d*BATCH per tile

        // ---- Load A fragments for full K=256, 4 M-tiles (64 rows), to regs.
        // A layout (16x16x32 bf16): lane holds A[m = lane&15][k = g*8 + j].
        bf16x8 afrag[MTILES][8];
#pragma unroll
        for (int m = 0; m < MTILES; ++m) {
            const float* rowp = enc + (size_t)(rowbase + m * 16 + n) * DIM + g * 8;
#pragma unroll
            for (int s = 0; s < 8; ++s) {
                float4 f0 = *(const float4*)(rowp + s * 32);
                float4 f1 = *(const float4*)(rowp + s * 32 + 4);
                bf16x8 a;
                a[0] = f2bf(f0.x); a[1] = f2bf(f0.y); a[2] = f2bf(f0.z); a[3] = f2bf(f0.w);
                a[4] = f2bf(f1.x); a[5] = f2bf(f1.y); a[6] = f2bf(f1.z); a[7] = f2bf(f1.w);
                afrag[m][s] = a;
            }
        }

        float u[MTILES][4];
#pragma unroll
        for (int m = 0; m < MTILES; ++m)
#pragma unroll
            for (int rg = 0; rg < 4; ++rg) u[m][rg] = 0.f;

        // ---- 16 n-tiles of d; full e-reduction per tile, fused epilogue.
#pragma unroll
        for (int t = 0; t < 16; ++t) {
            const int d = t * 16 + n;
            floatx4 acc[MTILES];
#pragma unroll
            for (int m = 0; m < MTILES; ++m) acc[m] = (floatx4){0.f, 0.f, 0.f, 0.f};
#pragma unroll
            for (int s = 0; s < 8; ++s) {
                // B layout: lane holds B[k=g*8+j][n] = Wref[d][e=s*32+g*8+j]
                short8 raw = *(const short8*)&wlds[d * DIM + (((s * 4 + g) ^ n) << 3)];
                bf16x8 bfrag = __builtin_bit_cast(bf16x8, raw);
#pragma unroll
                for (int m = 0; m < MTILES; ++m)
                    acc[m] = __builtin_amdgcn_mfma_f32_16x16x32_bf16(
                        afrag[m][s], bfrag, acc[m], 0, 0, 0);
            }
            const float vd = vreg[t];
            const float* qrow = qbase + (size_t)d * BATCH;
            // C/D layout: col = lane&15 (=d residue), row = g*4 + reg
#pragma unroll
            for (int m = 0; m < MTILES; ++m) {
                float4 qf = *(const float4*)(qrow + m * 16);
                u[m][0] += vd * fast_tanh(acc[m][0] + qf.x);
                u[m][1] += vd * fast_tanh(acc[m][1] + qf.y);
                u[m][2] += vd * fast_tanh(acc[m][2] + qf.z);
                u[m][3] += vd * fast_tanh(acc[m][3] + qf.w);
            }
        }

        // ---- Reduce u over the 16 lanes of each quad-group, store logits.
#pragma unroll
        for (int m = 0; m < MTILES; ++m) {
#pragma unroll
            for (int rg = 0; rg < 4; ++rg) {
                float s = u[m][rg];
                s += __shfl_xor(s, 1);
                s += __shfl_xor(s, 2);
                s += __shfl_xor(s, 4);
                s += __shfl_xor(s, 8);
                if (n == 0) {
                    const int r = rowbase + m * 16 + g * 4 + rg;  // r = k*BATCH + b
                    out[(size_t)(r & 255) * KSEQ + (r >> 8)] = 10.0f * fast_tanh(s);
                }
            }
        }
    }
}

extern "C" void kernel_launch(void* const* d_in, const int* in_sizes, int n_in,
                              void* d_out, int out_size, void* d_ws, size_t ws_size,
                              hipStream_t stream) {
    const float* enc   = (const float*)d_in[0];
    const float* query = (const float*)d_in[1];
    const float* Wq    = (const float*)d_in[2];
    const float* bq    = (const float*)d_in[3];
    const float* Wref  = (const float*)d_in[4];
    const float* bref  = (const float*)d_in[5];
    const float* v     = (const float*)d_in[6];
    float* out  = (float*)d_out;
    float* qpbT = (float*)d_ws;   // 256*256*4 = 256 KiB scratch

    qpb_kernel<<<BATCH, DIM, 0, stream>>>(query, Wq, bq, bref, qpbT);
    attn_kernel<<<BLOCKS, 512, 0, stream>>>(enc, qpbT, Wref, v, out);
}

// Round 3
// 759.512 us; speedup vs baseline: 2.6292x; 2.6292x over previous
//
#include <hip/hip_runtime.h>

#define DIM   256
#define KSEQ  2048
#define BATCH 256
#define NROWS (KSEQ * BATCH)          // 524288 flattened (k,b) rows
#define STRIPROWS 64
#define NSTRIPS (NROWS / STRIPROWS)   // 8192
#define BLOCKS 256
#define SPB (NSTRIPS / BLOCKS)        // 32 strips per block, contiguous

typedef __attribute__((ext_vector_type(8))) __bf16 bf16x8;
typedef __attribute__((ext_vector_type(4))) float  floatx4;
typedef __attribute__((ext_vector_type(8))) short  short8;

__device__ __forceinline__ unsigned short f2bf_bits(float f) {
    unsigned u = __builtin_bit_cast(unsigned, f);
    u += 0x7fffu + ((u >> 16) & 1u);          // round-to-nearest-even
    return (unsigned short)(u >> 16);
}

__device__ __forceinline__ float fast_tanh(float x) {
    float e = __expf(2.0f * x);
    return 1.0f - 2.0f * __builtin_amdgcn_rcpf(e + 1.0f);
}

__device__ __forceinline__ short8 pack_bf16x8(float4 f0, float4 f1) {
    short8 sv;
    sv[0] = (short)f2bf_bits(f0.x); sv[1] = (short)f2bf_bits(f0.y);
    sv[2] = (short)f2bf_bits(f0.z); sv[3] = (short)f2bf_bits(f0.w);
    sv[4] = (short)f2bf_bits(f1.x); sv[5] = (short)f2bf_bits(f1.y);
    sv[6] = (short)f2bf_bits(f1.z); sv[7] = (short)f2bf_bits(f1.w);
    return sv;
}

// Kernel 1: qpbT[d,b] = sum_e query[b,e]*Wq[d,e] + bq[d] + bref[d]  (transposed)
__global__ void qpb_kernel(const float* __restrict__ query,
                           const float* __restrict__ Wq,
                           const float* __restrict__ bq,
                           const float* __restrict__ bref,
                           float* __restrict__ qpbT) {
    __shared__ float qs[DIM];
    const int b = blockIdx.x;
    const int d = threadIdx.x;
    qs[d] = query[b * DIM + d];
    __syncthreads();
    const float* wrow = Wq + d * DIM;
    float acc = 0.f;
#pragma unroll 8
    for (int e = 0; e < DIM; ++e) acc += qs[e] * wrow[e];
    qpbT[d * BATCH + b] = acc + bq[d] + bref[d];
}

// Kernel 2: A (enc) staged through double-buffered LDS as bf16; B (Wref)
// persistent in registers (each wave owns a 32-wide d-slice); fused
// tanh-dot epilogue with cross-wave reduction, output deferred one strip.
__global__ __launch_bounds__(512, 1) void attn_kernel(
        const float* __restrict__ enc,    // (NROWS, DIM) fp32
        const float* __restrict__ qpbT,   // (DIM, BATCH) fp32 = q + bref
        const float* __restrict__ Wref,   // (DIM, DIM) fp32
        const float* __restrict__ v,      // (DIM,)
        float* __restrict__ out) {        // (BATCH, KSEQ)
    __shared__ short abuf[2][STRIPROWS * DIM];   // 2 x 32 KiB bf16 A tiles
    __shared__ float ured[2][8 * STRIPROWS];     // 2 x 2 KiB cross-wave partials

    const int tid  = threadIdx.x;
    const int lane = tid & 63;
    const int wave = tid >> 6;      // 0..7 -> d-slice [wave*32, wave*32+32)
    const int n    = lane & 15;
    const int g    = lane >> 4;

    // ---- Persistent B fragments: bfrag[tt][s] = Wref[d][e=s*32+g*8 ..+8], bf16.
    bf16x8 bfrag[2][8];
    float vreg[2];
#pragma unroll
    for (int tt = 0; tt < 2; ++tt) {
        const int d = wave * 32 + tt * 16 + n;
        vreg[tt] = v[d];
#pragma unroll
        for (int s = 0; s < 8; ++s) {
            const float* src = Wref + d * DIM + s * 32 + g * 8;
            float4 f0 = *(const float4*)(src);
            float4 f1 = *(const float4*)(src + 4);
            bfrag[tt][s] = __builtin_bit_cast(bf16x8, pack_bf16x8(f0, f1));
        }
    }

    const int base_strip = blockIdx.x * SPB;

    // ---- Prefetch registers for A staging: 4 chunks of 32B fp32 per thread.
    float4 areg[8];
#pragma unroll
    for (int it = 0; it < 4; ++it) {
        const int flat = it * 512 + tid;              // 2048 chunks/strip
        const int row  = flat >> 5;
        const int c    = flat & 31;
        const float* p = enc + (size_t)(base_strip * STRIPROWS + row) * DIM + c * 8;
        areg[it * 2]     = *(const float4*)(p);
        areg[it * 2 + 1] = *(const float4*)(p + 4);
    }

    for (int i = 0; i < SPB; ++i) {
        const int rowbase = (base_strip + i) * STRIPROWS;

        // ---- Convert prefetched A to bf16, write to abuf[i&1] (xor swizzle).
        short* bufw = &abuf[i & 1][0];
#pragma unroll
        for (int it = 0; it < 4; ++it) {
            const int flat = it * 512 + tid;
            const int row  = flat >> 5;
            const int c    = flat & 31;
            short8 sv = pack_bf16x8(areg[it * 2], areg[it * 2 + 1]);
            *(short8*)&bufw[row * DIM + ((c ^ (row & 15)) << 3)] = sv;
        }

        // ---- Issue next strip's global loads (latency hidden by compute).
        if (i + 1 < SPB) {
#pragma unroll
            for (int it = 0; it < 4; ++it) {
                const int flat = it * 512 + tid;
                const int row  = flat >> 5;
                const int c    = flat & 31;
                const float* p = enc + (size_t)(rowbase + STRIPROWS + row) * DIM + c * 8;
                areg[it * 2]     = *(const float4*)(p);
                areg[it * 2 + 1] = *(const float4*)(p + 4);
            }
        }

        __syncthreads();   // abuf[i&1] ready; ured[(i-1)&1] complete

        // ---- Deferred output of previous strip (one wave, 64 rows).
        if (i > 0 && tid < 64) {
            float s = 0.f;
#pragma unroll
            for (int w = 0; w < 8; ++w) s += ured[(i - 1) & 1][w * 64 + tid];
            const int r = rowbase - STRIPROWS + tid;       // r = k*BATCH + b
            out[(size_t)(r & 255) * KSEQ + (r >> 8)] = 10.0f * fast_tanh(s);
        }

        // ---- MFMA: 4 M-tiles x 2 d-tiles, K=256 in 8 steps.
        const short* bufr = &abuf[i & 1][0];
        floatx4 acc[2][4];
#pragma unroll
        for (int tt = 0; tt < 2; ++tt)
#pragma unroll
            for (int m = 0; m < 4; ++m) acc[tt][m] = (floatx4){0.f, 0.f, 0.f, 0.f};

#pragma unroll
        for (int s = 0; s < 8; ++s) {
            bf16x8 af[4];
#pragma unroll
            for (int m = 0; m < 4; ++m) {
                short8 raw = *(const short8*)&bufr[(m * 16 + n) * DIM +
                                                  (((s * 4 + g) ^ n) << 3)];
                af[m] = __builtin_bit_cast(bf16x8, raw);
            }
#pragma unroll
            for (int m = 0; m < 4; ++m) {
#pragma unroll
                for (int tt = 0; tt < 2; ++tt)
                    acc[tt][m] = __builtin_amdgcn_mfma_f32_16x16x32_bf16(
                        af[m], bfrag[tt][s], acc[tt][m], 0, 0, 0);
            }
        }

        // ---- Fused epilogue: u[m][rg] = sum over this wave's 32 d's.
        const int bbase = rowbase & 255;
        float u[4][4];
#pragma unroll
        for (int m = 0; m < 4; ++m)
#pragma unroll
            for (int rg = 0; rg < 4; ++rg) u[m][rg] = 0.f;

#pragma unroll
        for (int tt = 0; tt < 2; ++tt) {
            const int d = wave * 32 + tt * 16 + n;
            const float vd = vreg[tt];
            const float* qrow = qpbT + (size_t)d * BATCH + bbase + g * 4;
#pragma unroll
            for (int m = 0; m < 4; ++m) {
                float4 qf = *(const float4*)(qrow + m * 16);
                u[m][0] += vd * fast_tanh(acc[tt][m][0] + qf.x);
                u[m][1] += vd * fast_tanh(acc[tt][m][1] + qf.y);
                u[m][2] += vd * fast_tanh(acc[tt][m][2] + qf.z);
                u[m][3] += vd * fast_tanh(acc[tt][m][3] + qf.w);
            }
        }

        // ---- Reduce over the 16 n-lanes; lane n==0 writes per-row partials.
#pragma unroll
        for (int m = 0; m < 4; ++m) {
#pragma unroll
            for (int rg = 0; rg < 4; ++rg) {
                float s = u[m][rg];
                s += __shfl_xor(s, 1);
                s += __shfl_xor(s, 2);
                s += __shfl_xor(s, 4);
                s += __shfl_xor(s, 8);
                if (n == 0)
                    ured[i & 1][wave * 64 + m * 16 + g * 4 + rg] = s;
            }
        }
    }

    // ---- Flush last strip.
    __syncthreads();
    if (tid < 64) {
        float s = 0.f;
#pragma unroll
        for (int w = 0; w < 8; ++w) s += ured[(SPB - 1) & 1][w * 64 + tid];
        const int r = (base_strip + SPB - 1) * STRIPROWS + tid;
        out[(size_t)(r & 255) * KSEQ + (r >> 8)] = 10.0f * fast_tanh(s);
    }
}

extern "C" void kernel_launch(void* const* d_in, const int* in_sizes, int n_in,
                              void* d_out, int out_size, void* d_ws, size_t ws_size,
                              hipStream_t stream) {
    const float* enc   = (const float*)d_in[0];
    const float* query = (const float*)d_in[1];
    const float* Wq    = (const float*)d_in[2];
    const float* bq    = (const float*)d_in[3];
    const float* Wref  = (const float*)d_in[4];
    const float* bref  = (const float*)d_in[5];
    const float* v     = (const float*)d_in[6];
    float* out  = (float*)d_out;
    float* qpbT = (float*)d_ws;   // 256 KiB scratch

    qpb_kernel<<<BATCH, DIM, 0, stream>>>(query, Wq, bq, bref, qpbT);
    attn_kernel<<<BLOCKS, 512, 0, stream>>>(enc, qpbT, Wref, v, out);
}